// Round 22
// baseline (1088.849 us; speedup 1.0000x reference)
//
#include <hip/hip_runtime.h>
#include <hip/hip_bf16.h>
#include <math.h>

#define BB 8
#define NN 2048
#define KK 10
#define BN (BB * NN)
#define HC 1024            // cols per d2 half (2 halves = full 2048)
#define GCH 64             // point-chunks for fused l4 gathermax+gmax

typedef __attribute__((ext_vector_type(8))) short bf16x8;
typedef __attribute__((ext_vector_type(4))) float f32x4;

__device__ inline unsigned short f2bf(float f) {
    unsigned int u = __float_as_uint(f);
    unsigned int r = u + 0x7fffu + ((u >> 16) & 1u);
    return (unsigned short)(r >> 16);
}
__device__ inline float bf2f(unsigned short h) {
    return __uint_as_float((unsigned int)h << 16);
}

// async global->LDS DMA, 16 B/lane, dest = wave-uniform base + lane*16 [m97]
__device__ __forceinline__ void async16(const void* g, void* l) {
    __builtin_amdgcn_global_load_lds(
        (const __attribute__((address_space(1))) void*)g,
        (__attribute__((address_space(3))) void*)l, 16, 0, 0);
}

// ---------------------------------------------------------------------------
// Layer 0: split x (F=3) into hi/lo bf16 padded to 32, plus row sq-norms.
__global__ void xsplit3_kernel(const float* __restrict__ x,
                               unsigned short* __restrict__ hi,
                               unsigned short* __restrict__ lo,
                               float* __restrict__ sq) {
    int row = blockIdx.x * blockDim.x + threadIdx.x;
    if (row >= BN) return;
    unsigned short hbuf[32], lbuf[32];
#pragma unroll
    for (int f = 0; f < 32; ++f) { hbuf[f] = 0; lbuf[f] = 0; }
    float s = 0.f;
#pragma unroll
    for (int f = 0; f < 3; ++f) {
        float v = x[(size_t)row * 3 + f];
        s += v * v;
        unsigned short h = f2bf(v);
        hbuf[f] = h;
        lbuf[f] = f2bf(v - bf2f(h));
    }
    sq[row] = s;
#pragma unroll
    for (int f = 0; f < 32; f += 8) {
        *(uint4*)&hi[(size_t)row * 32 + f] = *(uint4*)&hbuf[f];
        *(uint4*)&lo[(size_t)row * 32 + f] = *(uint4*)&lbuf[f];
    }
}

// ---------------------------------------------------------------------------
// All 5 layers' WT built in ONE launch (weights are layer-static).
__global__ void wsplit_all_kernel(const float* __restrict__ w0, const float* __restrict__ w1,
                                  const float* __restrict__ w2, const float* __restrict__ w3,
                                  const float* __restrict__ w4, unsigned short* __restrict__ WTall) {
    const int fins[5]  = {3, 64, 128, 256, 512};
    const int fpads[5] = {32, 64, 128, 256, 512};
    const int fouts[5] = {64, 128, 256, 512, 1024};
    const int eoff[6]  = {0, 4096, 20480, 86016, 348160, 1396736};
    const int woff[5]  = {0, 8192, 40960, 172032, 696320};
    int i = blockIdx.x * blockDim.x + threadIdx.x;
    if (i >= 1396736) return;
    int l;
    if (i < eoff[1]) l = 0; else if (i < eoff[2]) l = 1;
    else if (i < eoff[3]) l = 2; else if (i < eoff[4]) l = 3; else l = 4;
    int e = i - eoff[l];
    const float* w = (l == 0) ? w0 : (l == 1) ? w1 : (l == 2) ? w2 : (l == 3) ? w3 : w4;
    int fin = fins[l], fpad = fpads[l], fout = fouts[l];
    unsigned short* WT = WTall + woff[l];
    int op = e % (2 * fout);
    int f = e / (2 * fout);
    float v = 0.f;
    if (f < fin) {
        if (op < fout) v = w[(size_t)f * fout + op] - w[(size_t)(fin + f) * fout + op];
        else v = w[(size_t)(fin + f) * fout + (op - fout)];
    }
    unsigned short h = f2bf(v);
    unsigned short lo = f2bf(v - bf2f(h));
    WT[(size_t)op * (2 * fpad) + f] = h;
    WT[(size_t)op * (2 * fpad) + fpad + f] = lo;
}

// ---------------------------------------------------------------------------
// kNN Gram GEMM (validated round 18/20, verbatim): SYMMETRIC upper-triangle
// tiles, mirror via 64x129 LDS transpose; bf16 hi/lo 3-phase MFMA; async16;
// XOR swizzle.
__global__ __launch_bounds__(256) void knn_gram_kernel(
        const unsigned short* __restrict__ xh, const unsigned short* __restrict__ xl,
        const float* __restrict__ sq, float* __restrict__ d2a,
        float* __restrict__ d2b, int F) {
    int b = blockIdx.y;
    int t = blockIdx.x, ti = 0;
    while (t >= 16 - ti) { t -= 16 - ti; ti++; }
    int tj = ti + t;
    int row0 = ti * 128;
    int col0 = tj * 128;
    const unsigned short* xhb = xh + (size_t)b * NN * F;
    const unsigned short* xlb = xl + (size_t)b * NN * F;
    const float* sqb = sq + (size_t)b * NN;

    __shared__ __align__(16) unsigned char smem_raw[33024];
    unsigned short* Ah = (unsigned short*)smem_raw;
    unsigned short* Al = Ah + 128 * 32;
    unsigned short* Bh = Al + 128 * 32;
    unsigned short* Bl = Bh + 128 * 32;
    float* LT = (float*)smem_raw;

    int tid = threadIdx.x;
    int lane = tid & 63;
    int wave = tid >> 6;
    int wr = (wave >> 1) * 64, wc = (wave & 1) * 64;
    int l15 = lane & 15, kq = lane >> 4;
    int rsub = lane >> 2;
    int csub = (((lane & 3) ^ ((lane >> 3) & 3))) * 8;
    int kqs = (kq ^ ((l15 >> 1) & 3)) * 8;

    f32x4 acc[4][4];
#pragma unroll
    for (int mt = 0; mt < 4; ++mt)
#pragma unroll
        for (int nt = 0; nt < 4; ++nt) acc[mt][nt] = (f32x4){0.f, 0.f, 0.f, 0.f};

    for (int kc = 0; kc < F; kc += 32) {
        __syncthreads();
#pragma unroll
        for (int j = 0; j < 2; ++j) {
            int row = wave * 32 + j * 16 + rsub;
            int dsto = wave * 1024 + j * 512;
            async16(xhb + (size_t)(row0 + row) * F + kc + csub, Ah + dsto);
            async16(xlb + (size_t)(row0 + row) * F + kc + csub, Al + dsto);
            async16(xhb + (size_t)(col0 + row) * F + kc + csub, Bh + dsto);
            async16(xlb + (size_t)(col0 + row) * F + kc + csub, Bl + dsto);
        }
        __syncthreads();
        bf16x8 bh[4], bl[4];
#pragma unroll
        for (int t4 = 0; t4 < 4; ++t4) {
            bh[t4] = *(const bf16x8*)&Bh[(wc + t4 * 16 + l15) * 32 + kqs];
            bl[t4] = *(const bf16x8*)&Bl[(wc + t4 * 16 + l15) * 32 + kqs];
        }
#pragma unroll
        for (int mt = 0; mt < 4; ++mt) {
            bf16x8 ah = *(const bf16x8*)&Ah[(wr + mt * 16 + l15) * 32 + kqs];
            bf16x8 al = *(const bf16x8*)&Al[(wr + mt * 16 + l15) * 32 + kqs];
#pragma unroll
            for (int nt = 0; nt < 4; ++nt) {
                acc[mt][nt] = __builtin_amdgcn_mfma_f32_16x16x32_bf16(ah, bh[nt], acc[mt][nt], 0, 0, 0);
                acc[mt][nt] = __builtin_amdgcn_mfma_f32_16x16x32_bf16(al, bh[nt], acc[mt][nt], 0, 0, 0);
                acc[mt][nt] = __builtin_amdgcn_mfma_f32_16x16x32_bf16(ah, bl[nt], acc[mt][nt], 0, 0, 0);
            }
        }
    }
    {
        float* dst = (col0 < HC) ? d2a : d2b;
        int lc0 = col0 & (HC - 1);
#pragma unroll
        for (int mt = 0; mt < 4; ++mt) {
            int rbase = row0 + wr + mt * 16 + kq * 4;
#pragma unroll
            for (int nt = 0; nt < 4; ++nt) {
                int cc = wc + nt * 16 + l15;
                float sqc = sqb[col0 + cc];
#pragma unroll
                for (int r = 0; r < 4; ++r) {
                    float v = (sqb[rbase + r] + sqc) - 2.f * acc[mt][nt][r];
                    acc[mt][nt][r] = v;
                    dst[((size_t)b * NN + rbase + r) * HC + lc0 + cc] = v;
                }
            }
        }
    }
    if (ti != tj) {
        float* mdst = (row0 < HC) ? d2a : d2b;
        int mc0 = row0 & (HC - 1);
#pragma unroll
        for (int h = 0; h < 2; ++h) {
            __syncthreads();
            if ((wave & 1) == h) {
#pragma unroll
                for (int mt = 0; mt < 4; ++mt)
#pragma unroll
                    for (int nt = 0; nt < 4; ++nt)
#pragma unroll
                        for (int r = 0; r < 4; ++r)
                            LT[(nt * 16 + l15) * 129 + (wr + mt * 16 + kq * 4 + r)] =
                                acc[mt][nt][r];
            }
            __syncthreads();
#pragma unroll
            for (int it = 0; it < 8; ++it) {
                int v = tid + it * 256;
                int lr = v >> 5, c4 = v & 31;
                float4 val;
                val.x = LT[lr * 129 + c4 * 4];
                val.y = LT[lr * 129 + c4 * 4 + 1];
                val.z = LT[lr * 129 + c4 * 4 + 2];
                val.w = LT[lr * 129 + c4 * 4 + 3];
                *(float4*)&mdst[((size_t)b * NN + col0 + h * 64 + lr) * HC + mc0 + c4 * 4] = val;
            }
        }
    }
}

// ---------------------------------------------------------------------------
// kNN selection (validated round 15): WAVE-PER-ROW, no LDS, no barriers.
__global__ __launch_bounds__(256) void knn_select_kernel(
        const float* __restrict__ d2a, const float* __restrict__ d2b,
        int* __restrict__ idx) {
    int row = blockIdx.x * 4 + (threadIdx.x >> 6);
    int lane = threadIdx.x & 63;
    const float* ra = d2a + (size_t)row * HC;
    const float* rb = d2b + (size_t)row * HC;

    float4 v[8];
#pragma unroll
    for (int it = 0; it < 4; ++it) {
        v[it]     = *(const float4*)&ra[it * 256 + lane * 4];
        v[it + 4] = *(const float4*)&rb[it * 256 + lane * 4];
    }

    float bestd[KK];
    int besti[KK];
#pragma unroll
    for (int k = 0; k < KK; ++k) { bestd[k] = INFINITY; besti[k] = 0x7fffffff; }

#pragma unroll
    for (int it = 0; it < 8; ++it) {
        int cbase = ((it < 4) ? (it * 256) : (HC + (it - 4) * 256)) + lane * 4;
        float dv[4] = {v[it].x, v[it].y, v[it].z, v[it].w};
#pragma unroll
        for (int s4 = 0; s4 < 4; ++s4) {
            float d = dv[s4];
            if (d < bestd[KK - 1]) {
                bestd[KK - 1] = d;
                besti[KK - 1] = cbase + s4;
#pragma unroll
                for (int s = KK - 1; s > 0; --s) {
                    if (bestd[s] < bestd[s - 1]) {
                        float td = bestd[s]; bestd[s] = bestd[s - 1]; bestd[s - 1] = td;
                        int ti = besti[s]; besti[s] = besti[s - 1]; besti[s - 1] = ti;
                    }
                }
            }
        }
    }

    int h = 0;
    int mywin = 0;
    for (int s = 0; s < KK; ++s) {
        float dd = (h < KK) ? bestd[h] : INFINITY;
        int ii = (h < KK) ? besti[h] : 0x7fffffff;
        float d0 = dd; int i0 = ii;
#pragma unroll
        for (int off = 32; off > 0; off >>= 1) {
            float od = __shfl_xor(dd, off);
            int oi = __shfl_xor(ii, off);
            if (od < dd || (od == dd && oi < ii)) { dd = od; ii = oi; }
        }
        if (lane == s) mywin = ii;
        if (h < KK && i0 == ii && d0 == dd) h++;
    }
    if (lane < KK) idx[(size_t)row * KK + lane] = mywin;
}

// ---------------------------------------------------------------------------
// MFMA GEMM (validated rounds 16/17/20, verbatim): single-pass 4-tile staging
// + XOR swizzle. LDS 32 KB.
__global__ __launch_bounds__(256) void gemm2_mfma_kernel(
        const unsigned short* __restrict__ XSh, const unsigned short* __restrict__ XSl,
        const unsigned short* __restrict__ WT, const float* __restrict__ bias,
        float* __restrict__ Aout, float* __restrict__ Tout, int fin, int fout) {
    int m0 = blockIdx.x * 128;
    int n0 = blockIdx.y * 128;
    __shared__ __align__(16) unsigned short AsB[4 * 128 * 32];   // 32 KB
    unsigned short* Ah = AsB;
    unsigned short* Al = Ah + 128 * 32;
    unsigned short* Bh = Al + 128 * 32;
    unsigned short* Bl = Bh + 128 * 32;

    int tid = threadIdx.x;
    int lane = tid & 63;
    int wave = tid >> 6;
    int wr = (wave >> 1) * 64, wc = (wave & 1) * 64;
    int l15 = lane & 15, kq = lane >> 4;
    int rsub = lane >> 2;
    int csub = (((lane & 3) ^ ((lane >> 3) & 3))) * 8;
    int kqs = (kq ^ ((l15 >> 1) & 3)) * 8;
    int w2f = 2 * fin;

    f32x4 acc[4][4];
#pragma unroll
    for (int mt = 0; mt < 4; ++mt)
#pragma unroll
        for (int nt = 0; nt < 4; ++nt) acc[mt][nt] = (f32x4){0.f, 0.f, 0.f, 0.f};

    for (int kc = 0; kc < fin; kc += 32) {
        __syncthreads();
#pragma unroll
        for (int j = 0; j < 2; ++j) {
            int row = wave * 32 + j * 16 + rsub;
            int dsto = wave * 1024 + j * 512;
            async16(XSh + (size_t)(m0 + row) * fin + kc + csub, Ah + dsto);
            async16(XSl + (size_t)(m0 + row) * fin + kc + csub, Al + dsto);
            async16(WT + (size_t)(n0 + row) * w2f + kc + csub, Bh + dsto);
            async16(WT + (size_t)(n0 + row) * w2f + fin + kc + csub, Bl + dsto);
        }
        __syncthreads();
        bf16x8 bh[4], bl[4];
#pragma unroll
        for (int t = 0; t < 4; ++t) {
            bh[t] = *(const bf16x8*)&Bh[(wc + t * 16 + l15) * 32 + kqs];
            bl[t] = *(const bf16x8*)&Bl[(wc + t * 16 + l15) * 32 + kqs];
        }
#pragma unroll
        for (int mt = 0; mt < 4; ++mt) {
            bf16x8 ah = *(const bf16x8*)&Ah[(wr + mt * 16 + l15) * 32 + kqs];
            bf16x8 al = *(const bf16x8*)&Al[(wr + mt * 16 + l15) * 32 + kqs];
#pragma unroll
            for (int nt = 0; nt < 4; ++nt) {
                acc[mt][nt] = __builtin_amdgcn_mfma_f32_16x16x32_bf16(ah, bh[nt], acc[mt][nt], 0, 0, 0);
                acc[mt][nt] = __builtin_amdgcn_mfma_f32_16x16x32_bf16(al, bh[nt], acc[mt][nt], 0, 0, 0);
                acc[mt][nt] = __builtin_amdgcn_mfma_f32_16x16x32_bf16(ah, bl[nt], acc[mt][nt], 0, 0, 0);
            }
        }
    }
#pragma unroll
    for (int mt = 0; mt < 4; ++mt) {
        int mbase = m0 + wr + mt * 16 + kq * 4;
#pragma unroll
        for (int nt = 0; nt < 4; ++nt) {
            int oc = n0 + wc + nt * 16 + l15;
            f32x4 c = acc[mt][nt];
            if (oc < fout) {
                float bv = bias[oc];
#pragma unroll
                for (int r = 0; r < 4; ++r)
                    Aout[(size_t)(mbase + r) * fout + oc] = c[r] + bv;
            } else {
                int o2 = oc - fout;
#pragma unroll
                for (int r = 0; r < 4; ++r)
                    Tout[(size_t)(mbase + r) * fout + o2] = c[r];
            }
        }
    }
}

// ---------------------------------------------------------------------------
// FUSED gathermax (layers 0-3): wave-per-row; writes bf16 splits + sq only.
__global__ __launch_bounds__(256) void gathermax_fused_kernel(
        const float* __restrict__ A, const float* __restrict__ T,
        const int* __restrict__ idx, unsigned short* __restrict__ hi,
        unsigned short* __restrict__ lo, float* __restrict__ sq, int shift) {
    int b = blockIdx.y;
    int wave = threadIdx.x >> 6;
    int lane = threadIdx.x & 63;
    int pnl = blockIdx.x * 4 + wave;
    int pn = (b << 11) + pnl;
    int fout = 1 << shift;
    int nf4 = fout >> 2;
    const float* Tb = T + ((size_t)b << 11) * fout;
    const int* ip = idx + (size_t)pn * KK;
    int j[KK];
#pragma unroll
    for (int k = 0; k < KK; ++k) j[k] = ip[k];

    float s = 0.f;
    for (int f4 = lane; f4 < nf4; f4 += 64) {
        int o = f4 * 4;
        float4 m = {-INFINITY, -INFINITY, -INFINITY, -INFINITY};
#pragma unroll
        for (int k = 0; k < KK; ++k) {
            float4 t = *(const float4*)&Tb[(size_t)j[k] * fout + o];
            m.x = fmaxf(m.x, t.x); m.y = fmaxf(m.y, t.y);
            m.z = fmaxf(m.z, t.z); m.w = fmaxf(m.w, t.w);
        }
        float4 a = *(const float4*)&A[(size_t)pn * fout + o];
        float h4[4];
        h4[0] = a.x + m.x; h4[1] = a.y + m.y; h4[2] = a.z + m.z; h4[3] = a.w + m.w;
        uint2 uh, ul;
        unsigned short hs[4], ls[4];
#pragma unroll
        for (int q = 0; q < 4; ++q) {
            float h = h4[q] > 0.f ? h4[q] : 0.2f * h4[q];
            s += h * h;
            unsigned short hh = f2bf(h);
            hs[q] = hh;
            ls[q] = f2bf(h - bf2f(hh));
        }
        uh.x = (unsigned)hs[0] | ((unsigned)hs[1] << 16);
        uh.y = (unsigned)hs[2] | ((unsigned)hs[3] << 16);
        ul.x = (unsigned)ls[0] | ((unsigned)ls[1] << 16);
        ul.y = (unsigned)ls[2] | ((unsigned)ls[3] << 16);
        *(uint2*)&hi[(size_t)pn * fout + o] = uh;
        *(uint2*)&lo[(size_t)pn * fout + o] = ul;
    }
#pragma unroll
    for (int off = 32; off > 0; off >>= 1) s += __shfl_down(s, off);
    if (lane == 0) sq[pn] = s;
}

// ---------------------------------------------------------------------------
// FUSED l4 gathermax + gmax pass 1 (validated round 20).
__global__ __launch_bounds__(256) void gathermax_gmax_kernel(
        const float* __restrict__ A, const float* __restrict__ T,
        const int* __restrict__ idx, float* __restrict__ gp) {
    int chunk = blockIdx.x;
    int b = blockIdx.y;
    int o = threadIdx.x * 4;
    const float* Tb = T + ((size_t)b << 11) * 1024;
    float4 gm = {-INFINITY, -INFINITY, -INFINITY, -INFINITY};
    for (int p = 0; p < NN / GCH; ++p) {
        int pnl = chunk * (NN / GCH) + p;
        int pn = (b << 11) + pnl;
        const int* ip = idx + (size_t)pn * KK;
        float4 m = {-INFINITY, -INFINITY, -INFINITY, -INFINITY};
#pragma unroll
        for (int k = 0; k < KK; ++k) {
            int j = ip[k];
            float4 t = *(const float4*)&Tb[(size_t)j * 1024 + o];
            m.x = fmaxf(m.x, t.x); m.y = fmaxf(m.y, t.y);
            m.z = fmaxf(m.z, t.z); m.w = fmaxf(m.w, t.w);
        }
        float4 a = *(const float4*)&A[(size_t)pn * 1024 + o];
        float4 h;
        h.x = a.x + m.x; h.y = a.y + m.y; h.z = a.z + m.z; h.w = a.w + m.w;
        h.x = h.x > 0.f ? h.x : 0.2f * h.x;
        h.y = h.y > 0.f ? h.y : 0.2f * h.y;
        h.z = h.z > 0.f ? h.z : 0.2f * h.z;
        h.w = h.w > 0.f ? h.w : 0.2f * h.w;
        gm.x = fmaxf(gm.x, h.x); gm.y = fmaxf(gm.y, h.y);
        gm.z = fmaxf(gm.z, h.z); gm.w = fmaxf(gm.w, h.w);
    }
    *(float4*)&gp[((size_t)chunk * BB + b) * 1024 + o] = gm;
}

// ---------------------------------------------------------------------------
// MLP with fused gmax pass 2 (reads the 64 partials directly; asc order).
__global__ __launch_bounds__(128) void mlp_kernel(const float* __restrict__ gp,
                                                  const float* __restrict__ m0w, const float* __restrict__ m0b,
                                                  const float* __restrict__ m1w, const float* __restrict__ m1b,
                                                  const float* __restrict__ m2w, const float* __restrict__ m2b,
                                                  float* __restrict__ out) {
    __shared__ float gs[1024];
    __shared__ float h1[128];
    __shared__ float h2[64];
    int b = blockIdx.x, t = threadIdx.x;
    for (int i = t; i < 1024; i += 128) {
        float m = -INFINITY;
        for (int c = 0; c < GCH; ++c) m = fmaxf(m, gp[((size_t)c * BB + b) * 1024 + i]);
        gs[i] = m;
    }
    __syncthreads();
    float s = m0b[t];
    for (int f = 0; f < 1024; ++f) s += gs[f] * m0w[(size_t)f * 128 + t];
    h1[t] = s;
    __syncthreads();
    if (t < 64) {
        float s2 = m1b[t];
        for (int f = 0; f < 128; ++f) s2 += h1[f] * m1w[(size_t)f * 64 + t];
        h2[t] = s2;
    }
    __syncthreads();
    if (t == 0) {
        float s3 = m2b[0];
        for (int f = 0; f < 64; ++f) s3 += h2[f] * m2w[f];
        out[b] = s3;
    }
}

// ---------------------------------------------------------------------------
extern "C" void kernel_launch(void* const* d_in, const int* in_sizes, int n_in,
                              void* d_out, int out_size, void* d_ws, size_t ws_size,
                              hipStream_t stream) {
    const float* x0 = (const float*)d_in[0];
    const float* w[5], * bi[5];
    for (int i = 0; i < 5; ++i) { w[i] = (const float*)d_in[1 + 2 * i]; bi[i] = (const float*)d_in[2 + 2 * i]; }
    const float* m0w = (const float*)d_in[11]; const float* m0b = (const float*)d_in[12];
    const float* m1w = (const float*)d_in[13]; const float* m1b = (const float*)d_in[14];
    const float* m2w = (const float*)d_in[15]; const float* m2b = (const float*)d_in[16];

    const int fouts[5] = {64, 128, 256, 512, 1024};
    const int shifts[5] = {6, 7, 8, 9, 10};
    const int woff[5] = {0, 8192, 40960, 172032, 696320};
    const size_t WTALL = 2793472;   // shorts

    // round-20 layout (validated): X0, X1, T, SQ, IDX, XS, WTall, GP
    float* X0 = (float*)d_ws;
    float* X1 = X0 + (size_t)BN * 1024;
    float* T  = X1 + (size_t)BN * 1024;
    float* SQ = T  + (size_t)BN * 1024;
    int*   IDX = (int*)(SQ + BN);
    unsigned short* XSh = (unsigned short*)(IDX + (size_t)BN * KK);
    unsigned short* XSl = XSh + (size_t)BN * 512;
    unsigned short* WTall = XSl + (size_t)BN * 512;
    float* GP = (float*)(WTall + WTALL);
    float* bufs[2] = {X0, X1};

    xsplit3_kernel<<<(BN + 255) / 256, 256, 0, stream>>>(x0, XSh, XSl, SQ);
    wsplit_all_kernel<<<(1396736 + 255) / 256, 256, 0, stream>>>(w[0], w[1], w[2], w[3], w[4], WTall);

    int fin = 3;
    for (int l = 0; l < 5; ++l) {
        int fout = fouts[l];
        float* nxt = bufs[l & 1];
        int Fg = (l == 0) ? 32 : fin;      // padded K for MFMA path

        // d2 halves: D2a = T, D2b = nxt (both dead until gemm2 writes them)
        dim3 gg2(136, BB);   // upper-triangle 128x128 tile pairs
        knn_gram_kernel<<<gg2, 256, 0, stream>>>(XSh, XSl, SQ, T, nxt, Fg);
        knn_select_kernel<<<BN / 4, 256, 0, stream>>>(T, nxt, IDX);

        dim3 gg(BN / 128, (2 * fout) / 128);
        gemm2_mfma_kernel<<<gg, 256, 0, stream>>>(XSh, XSl, WTall + woff[l], bi[l], nxt, T, Fg, fout);

        if (l < 4) {
            dim3 gmg(NN / 4, BB);
            gathermax_fused_kernel<<<gmg, 256, 0, stream>>>(nxt, T, IDX, XSh, XSl, SQ, shifts[l]);
        } else {
            dim3 gmg(GCH, BB);
            gathermax_gmax_kernel<<<gmg, 256, 0, stream>>>(nxt, T, IDX, GP);
        }

        fin = fout;
    }

    mlp_kernel<<<BB, 128, 0, stream>>>(GP, m0w, m0b, m1w, m1b, m2w, m2b, (float*)d_out);
}

// Round 23
// 967.941 us; speedup vs baseline: 1.1249x; 1.1249x over previous
//
#include <hip/hip_runtime.h>
#include <hip/hip_bf16.h>
#include <math.h>

#define BB 8
#define NN 2048
#define KK 10
#define BN (BB * NN)
#define HC 1024            // cols per d2 half (2 halves = full 2048)
#define GCH 64             // point-chunks for fused l4 gathermax+gmax

typedef __attribute__((ext_vector_type(8))) short bf16x8;
typedef __attribute__((ext_vector_type(4))) float f32x4;

__device__ inline unsigned short f2bf(float f) {
    unsigned int u = __float_as_uint(f);
    unsigned int r = u + 0x7fffu + ((u >> 16) & 1u);
    return (unsigned short)(r >> 16);
}
__device__ inline float bf2f(unsigned short h) {
    return __uint_as_float((unsigned int)h << 16);
}

// async global->LDS DMA, 16 B/lane, dest = wave-uniform base + lane*16 [m97]
__device__ __forceinline__ void async16(const void* g, void* l) {
    __builtin_amdgcn_global_load_lds(
        (const __attribute__((address_space(1))) void*)g,
        (__attribute__((address_space(3))) void*)l, 16, 0, 0);
}

// ---------------------------------------------------------------------------
// Layer 0: split x (F=3) into hi/lo bf16 padded to 32, plus row sq-norms.
__global__ void xsplit3_kernel(const float* __restrict__ x,
                               unsigned short* __restrict__ hi,
                               unsigned short* __restrict__ lo,
                               float* __restrict__ sq) {
    int row = blockIdx.x * blockDim.x + threadIdx.x;
    if (row >= BN) return;
    unsigned short hbuf[32], lbuf[32];
#pragma unroll
    for (int f = 0; f < 32; ++f) { hbuf[f] = 0; lbuf[f] = 0; }
    float s = 0.f;
#pragma unroll
    for (int f = 0; f < 3; ++f) {
        float v = x[(size_t)row * 3 + f];
        s += v * v;
        unsigned short h = f2bf(v);
        hbuf[f] = h;
        lbuf[f] = f2bf(v - bf2f(h));
    }
    sq[row] = s;
#pragma unroll
    for (int f = 0; f < 32; f += 8) {
        *(uint4*)&hi[(size_t)row * 32 + f] = *(uint4*)&hbuf[f];
        *(uint4*)&lo[(size_t)row * 32 + f] = *(uint4*)&lbuf[f];
    }
}

// ---------------------------------------------------------------------------
// All 5 layers' WT built in ONE launch (weights are layer-static).
__global__ void wsplit_all_kernel(const float* __restrict__ w0, const float* __restrict__ w1,
                                  const float* __restrict__ w2, const float* __restrict__ w3,
                                  const float* __restrict__ w4, unsigned short* __restrict__ WTall) {
    const int fins[5]  = {3, 64, 128, 256, 512};
    const int fpads[5] = {32, 64, 128, 256, 512};
    const int fouts[5] = {64, 128, 256, 512, 1024};
    const int eoff[6]  = {0, 4096, 20480, 86016, 348160, 1396736};
    const int woff[5]  = {0, 8192, 40960, 172032, 696320};
    int i = blockIdx.x * blockDim.x + threadIdx.x;
    if (i >= 1396736) return;
    int l;
    if (i < eoff[1]) l = 0; else if (i < eoff[2]) l = 1;
    else if (i < eoff[3]) l = 2; else if (i < eoff[4]) l = 3; else l = 4;
    int e = i - eoff[l];
    const float* w = (l == 0) ? w0 : (l == 1) ? w1 : (l == 2) ? w2 : (l == 3) ? w3 : w4;
    int fin = fins[l], fpad = fpads[l], fout = fouts[l];
    unsigned short* WT = WTall + woff[l];
    int op = e % (2 * fout);
    int f = e / (2 * fout);
    float v = 0.f;
    if (f < fin) {
        if (op < fout) v = w[(size_t)f * fout + op] - w[(size_t)(fin + f) * fout + op];
        else v = w[(size_t)(fin + f) * fout + (op - fout)];
    }
    unsigned short h = f2bf(v);
    unsigned short lo = f2bf(v - bf2f(h));
    WT[(size_t)op * (2 * fpad) + f] = h;
    WT[(size_t)op * (2 * fpad) + fpad + f] = lo;
}

// ---------------------------------------------------------------------------
// kNN Gram GEMM (validated round 18/20, verbatim): SYMMETRIC upper-triangle
// tiles, mirror via 64x129 LDS transpose; bf16 hi/lo 3-phase MFMA; async16;
// XOR swizzle.
__global__ __launch_bounds__(256) void knn_gram_kernel(
        const unsigned short* __restrict__ xh, const unsigned short* __restrict__ xl,
        const float* __restrict__ sq, float* __restrict__ d2a,
        float* __restrict__ d2b, int F) {
    int b = blockIdx.y;
    int t = blockIdx.x, ti = 0;
    while (t >= 16 - ti) { t -= 16 - ti; ti++; }
    int tj = ti + t;
    int row0 = ti * 128;
    int col0 = tj * 128;
    const unsigned short* xhb = xh + (size_t)b * NN * F;
    const unsigned short* xlb = xl + (size_t)b * NN * F;
    const float* sqb = sq + (size_t)b * NN;

    __shared__ __align__(16) unsigned char smem_raw[33024];
    unsigned short* Ah = (unsigned short*)smem_raw;
    unsigned short* Al = Ah + 128 * 32;
    unsigned short* Bh = Al + 128 * 32;
    unsigned short* Bl = Bh + 128 * 32;
    float* LT = (float*)smem_raw;

    int tid = threadIdx.x;
    int lane = tid & 63;
    int wave = tid >> 6;
    int wr = (wave >> 1) * 64, wc = (wave & 1) * 64;
    int l15 = lane & 15, kq = lane >> 4;
    int rsub = lane >> 2;
    int csub = (((lane & 3) ^ ((lane >> 3) & 3))) * 8;
    int kqs = (kq ^ ((l15 >> 1) & 3)) * 8;

    f32x4 acc[4][4];
#pragma unroll
    for (int mt = 0; mt < 4; ++mt)
#pragma unroll
        for (int nt = 0; nt < 4; ++nt) acc[mt][nt] = (f32x4){0.f, 0.f, 0.f, 0.f};

    for (int kc = 0; kc < F; kc += 32) {
        __syncthreads();
#pragma unroll
        for (int j = 0; j < 2; ++j) {
            int row = wave * 32 + j * 16 + rsub;
            int dsto = wave * 1024 + j * 512;
            async16(xhb + (size_t)(row0 + row) * F + kc + csub, Ah + dsto);
            async16(xlb + (size_t)(row0 + row) * F + kc + csub, Al + dsto);
            async16(xhb + (size_t)(col0 + row) * F + kc + csub, Bh + dsto);
            async16(xlb + (size_t)(col0 + row) * F + kc + csub, Bl + dsto);
        }
        __syncthreads();
        bf16x8 bh[4], bl[4];
#pragma unroll
        for (int t4 = 0; t4 < 4; ++t4) {
            bh[t4] = *(const bf16x8*)&Bh[(wc + t4 * 16 + l15) * 32 + kqs];
            bl[t4] = *(const bf16x8*)&Bl[(wc + t4 * 16 + l15) * 32 + kqs];
        }
#pragma unroll
        for (int mt = 0; mt < 4; ++mt) {
            bf16x8 ah = *(const bf16x8*)&Ah[(wr + mt * 16 + l15) * 32 + kqs];
            bf16x8 al = *(const bf16x8*)&Al[(wr + mt * 16 + l15) * 32 + kqs];
#pragma unroll
            for (int nt = 0; nt < 4; ++nt) {
                acc[mt][nt] = __builtin_amdgcn_mfma_f32_16x16x32_bf16(ah, bh[nt], acc[mt][nt], 0, 0, 0);
                acc[mt][nt] = __builtin_amdgcn_mfma_f32_16x16x32_bf16(al, bh[nt], acc[mt][nt], 0, 0, 0);
                acc[mt][nt] = __builtin_amdgcn_mfma_f32_16x16x32_bf16(ah, bl[nt], acc[mt][nt], 0, 0, 0);
            }
        }
    }
    {
        float* dst = (col0 < HC) ? d2a : d2b;
        int lc0 = col0 & (HC - 1);
#pragma unroll
        for (int mt = 0; mt < 4; ++mt) {
            int rbase = row0 + wr + mt * 16 + kq * 4;
#pragma unroll
            for (int nt = 0; nt < 4; ++nt) {
                int cc = wc + nt * 16 + l15;
                float sqc = sqb[col0 + cc];
#pragma unroll
                for (int r = 0; r < 4; ++r) {
                    float v = (sqb[rbase + r] + sqc) - 2.f * acc[mt][nt][r];
                    acc[mt][nt][r] = v;
                    dst[((size_t)b * NN + rbase + r) * HC + lc0 + cc] = v;
                }
            }
        }
    }
    if (ti != tj) {
        float* mdst = (row0 < HC) ? d2a : d2b;
        int mc0 = row0 & (HC - 1);
#pragma unroll
        for (int h = 0; h < 2; ++h) {
            __syncthreads();
            if ((wave & 1) == h) {
#pragma unroll
                for (int mt = 0; mt < 4; ++mt)
#pragma unroll
                    for (int nt = 0; nt < 4; ++nt)
#pragma unroll
                        for (int r = 0; r < 4; ++r)
                            LT[(nt * 16 + l15) * 129 + (wr + mt * 16 + kq * 4 + r)] =
                                acc[mt][nt][r];
            }
            __syncthreads();
#pragma unroll
            for (int it = 0; it < 8; ++it) {
                int v = tid + it * 256;
                int lr = v >> 5, c4 = v & 31;
                float4 val;
                val.x = LT[lr * 129 + c4 * 4];
                val.y = LT[lr * 129 + c4 * 4 + 1];
                val.z = LT[lr * 129 + c4 * 4 + 2];
                val.w = LT[lr * 129 + c4 * 4 + 3];
                *(float4*)&mdst[((size_t)b * NN + col0 + h * 64 + lr) * HC + mc0 + c4 * 4] = val;
            }
        }
    }
}

// ---------------------------------------------------------------------------
// kNN selection (validated round 15): WAVE-PER-ROW, no LDS, no barriers.
__global__ __launch_bounds__(256) void knn_select_kernel(
        const float* __restrict__ d2a, const float* __restrict__ d2b,
        int* __restrict__ idx) {
    int row = blockIdx.x * 4 + (threadIdx.x >> 6);
    int lane = threadIdx.x & 63;
    const float* ra = d2a + (size_t)row * HC;
    const float* rb = d2b + (size_t)row * HC;

    float4 v[8];
#pragma unroll
    for (int it = 0; it < 4; ++it) {
        v[it]     = *(const float4*)&ra[it * 256 + lane * 4];
        v[it + 4] = *(const float4*)&rb[it * 256 + lane * 4];
    }

    float bestd[KK];
    int besti[KK];
#pragma unroll
    for (int k = 0; k < KK; ++k) { bestd[k] = INFINITY; besti[k] = 0x7fffffff; }

#pragma unroll
    for (int it = 0; it < 8; ++it) {
        int cbase = ((it < 4) ? (it * 256) : (HC + (it - 4) * 256)) + lane * 4;
        float dv[4] = {v[it].x, v[it].y, v[it].z, v[it].w};
#pragma unroll
        for (int s4 = 0; s4 < 4; ++s4) {
            float d = dv[s4];
            if (d < bestd[KK - 1]) {
                bestd[KK - 1] = d;
                besti[KK - 1] = cbase + s4;
#pragma unroll
                for (int s = KK - 1; s > 0; --s) {
                    if (bestd[s] < bestd[s - 1]) {
                        float td = bestd[s]; bestd[s] = bestd[s - 1]; bestd[s - 1] = td;
                        int ti = besti[s]; besti[s] = besti[s - 1]; besti[s - 1] = ti;
                    }
                }
            }
        }
    }

    int h = 0;
    int mywin = 0;
    for (int s = 0; s < KK; ++s) {
        float dd = (h < KK) ? bestd[h] : INFINITY;
        int ii = (h < KK) ? besti[h] : 0x7fffffff;
        float d0 = dd; int i0 = ii;
#pragma unroll
        for (int off = 32; off > 0; off >>= 1) {
            float od = __shfl_xor(dd, off);
            int oi = __shfl_xor(ii, off);
            if (od < dd || (od == dd && oi < ii)) { dd = od; ii = oi; }
        }
        if (lane == s) mywin = ii;
        if (h < KK && i0 == ii && d0 == dd) h++;
    }
    if (lane < KK) idx[(size_t)row * KK + lane] = mywin;
}

// ---------------------------------------------------------------------------
// MFMA GEMM (validated rounds 16/17/20, verbatim): single-pass 4-tile staging
// + XOR swizzle. LDS 32 KB.
__global__ __launch_bounds__(256) void gemm2_mfma_kernel(
        const unsigned short* __restrict__ XSh, const unsigned short* __restrict__ XSl,
        const unsigned short* __restrict__ WT, const float* __restrict__ bias,
        float* __restrict__ Aout, float* __restrict__ Tout, int fin, int fout) {
    int m0 = blockIdx.x * 128;
    int n0 = blockIdx.y * 128;
    __shared__ __align__(16) unsigned short AsB[4 * 128 * 32];   // 32 KB
    unsigned short* Ah = AsB;
    unsigned short* Al = Ah + 128 * 32;
    unsigned short* Bh = Al + 128 * 32;
    unsigned short* Bl = Bh + 128 * 32;

    int tid = threadIdx.x;
    int lane = tid & 63;
    int wave = tid >> 6;
    int wr = (wave >> 1) * 64, wc = (wave & 1) * 64;
    int l15 = lane & 15, kq = lane >> 4;
    int rsub = lane >> 2;
    int csub = (((lane & 3) ^ ((lane >> 3) & 3))) * 8;
    int kqs = (kq ^ ((l15 >> 1) & 3)) * 8;
    int w2f = 2 * fin;

    f32x4 acc[4][4];
#pragma unroll
    for (int mt = 0; mt < 4; ++mt)
#pragma unroll
        for (int nt = 0; nt < 4; ++nt) acc[mt][nt] = (f32x4){0.f, 0.f, 0.f, 0.f};

    for (int kc = 0; kc < fin; kc += 32) {
        __syncthreads();
#pragma unroll
        for (int j = 0; j < 2; ++j) {
            int row = wave * 32 + j * 16 + rsub;
            int dsto = wave * 1024 + j * 512;
            async16(XSh + (size_t)(m0 + row) * fin + kc + csub, Ah + dsto);
            async16(XSl + (size_t)(m0 + row) * fin + kc + csub, Al + dsto);
            async16(WT + (size_t)(n0 + row) * w2f + kc + csub, Bh + dsto);
            async16(WT + (size_t)(n0 + row) * w2f + fin + kc + csub, Bl + dsto);
        }
        __syncthreads();
        bf16x8 bh[4], bl[4];
#pragma unroll
        for (int t = 0; t < 4; ++t) {
            bh[t] = *(const bf16x8*)&Bh[(wc + t * 16 + l15) * 32 + kqs];
            bl[t] = *(const bf16x8*)&Bl[(wc + t * 16 + l15) * 32 + kqs];
        }
#pragma unroll
        for (int mt = 0; mt < 4; ++mt) {
            bf16x8 ah = *(const bf16x8*)&Ah[(wr + mt * 16 + l15) * 32 + kqs];
            bf16x8 al = *(const bf16x8*)&Al[(wr + mt * 16 + l15) * 32 + kqs];
#pragma unroll
            for (int nt = 0; nt < 4; ++nt) {
                acc[mt][nt] = __builtin_amdgcn_mfma_f32_16x16x32_bf16(ah, bh[nt], acc[mt][nt], 0, 0, 0);
                acc[mt][nt] = __builtin_amdgcn_mfma_f32_16x16x32_bf16(al, bh[nt], acc[mt][nt], 0, 0, 0);
                acc[mt][nt] = __builtin_amdgcn_mfma_f32_16x16x32_bf16(ah, bl[nt], acc[mt][nt], 0, 0, 0);
            }
        }
    }
#pragma unroll
    for (int mt = 0; mt < 4; ++mt) {
        int mbase = m0 + wr + mt * 16 + kq * 4;
#pragma unroll
        for (int nt = 0; nt < 4; ++nt) {
            int oc = n0 + wc + nt * 16 + l15;
            f32x4 c = acc[mt][nt];
            if (oc < fout) {
                float bv = bias[oc];
#pragma unroll
                for (int r = 0; r < 4; ++r)
                    Aout[(size_t)(mbase + r) * fout + oc] = c[r] + bv;
            } else {
                int o2 = oc - fout;
#pragma unroll
                for (int r = 0; r < 4; ++r)
                    Tout[(size_t)(mbase + r) * fout + o2] = c[r];
            }
        }
    }
}

// ---------------------------------------------------------------------------
// FUSED gathermax (layers 0-3): wave-per-row; writes bf16 splits + sq only.
__global__ __launch_bounds__(256) void gathermax_fused_kernel(
        const float* __restrict__ A, const float* __restrict__ T,
        const int* __restrict__ idx, unsigned short* __restrict__ hi,
        unsigned short* __restrict__ lo, float* __restrict__ sq, int shift) {
    int b = blockIdx.y;
    int wave = threadIdx.x >> 6;
    int lane = threadIdx.x & 63;
    int pnl = blockIdx.x * 4 + wave;
    int pn = (b << 11) + pnl;
    int fout = 1 << shift;
    int nf4 = fout >> 2;
    const float* Tb = T + ((size_t)b << 11) * fout;
    const int* ip = idx + (size_t)pn * KK;
    int j[KK];
#pragma unroll
    for (int k = 0; k < KK; ++k) j[k] = ip[k];

    float s = 0.f;
    for (int f4 = lane; f4 < nf4; f4 += 64) {
        int o = f4 * 4;
        float4 m = {-INFINITY, -INFINITY, -INFINITY, -INFINITY};
#pragma unroll
        for (int k = 0; k < KK; ++k) {
            float4 t = *(const float4*)&Tb[(size_t)j[k] * fout + o];
            m.x = fmaxf(m.x, t.x); m.y = fmaxf(m.y, t.y);
            m.z = fmaxf(m.z, t.z); m.w = fmaxf(m.w, t.w);
        }
        float4 a = *(const float4*)&A[(size_t)pn * fout + o];
        float h4[4];
        h4[0] = a.x + m.x; h4[1] = a.y + m.y; h4[2] = a.z + m.z; h4[3] = a.w + m.w;
        uint2 uh, ul;
        unsigned short hs[4], ls[4];
#pragma unroll
        for (int q = 0; q < 4; ++q) {
            float h = h4[q] > 0.f ? h4[q] : 0.2f * h4[q];
            s += h * h;
            unsigned short hh = f2bf(h);
            hs[q] = hh;
            ls[q] = f2bf(h - bf2f(hh));
        }
        uh.x = (unsigned)hs[0] | ((unsigned)hs[1] << 16);
        uh.y = (unsigned)hs[2] | ((unsigned)hs[3] << 16);
        ul.x = (unsigned)ls[0] | ((unsigned)ls[1] << 16);
        ul.y = (unsigned)ls[2] | ((unsigned)ls[3] << 16);
        *(uint2*)&hi[(size_t)pn * fout + o] = uh;
        *(uint2*)&lo[(size_t)pn * fout + o] = ul;
    }
#pragma unroll
    for (int off = 32; off > 0; off >>= 1) s += __shfl_down(s, off);
    if (lane == 0) sq[pn] = s;
}

// ---------------------------------------------------------------------------
// FUSED l4 gathermax + gmax pass 1 (validated round 20).
__global__ __launch_bounds__(256) void gathermax_gmax_kernel(
        const float* __restrict__ A, const float* __restrict__ T,
        const int* __restrict__ idx, float* __restrict__ gp) {
    int chunk = blockIdx.x;
    int b = blockIdx.y;
    int o = threadIdx.x * 4;
    const float* Tb = T + ((size_t)b << 11) * 1024;
    float4 gm = {-INFINITY, -INFINITY, -INFINITY, -INFINITY};
    for (int p = 0; p < NN / GCH; ++p) {
        int pnl = chunk * (NN / GCH) + p;
        int pn = (b << 11) + pnl;
        const int* ip = idx + (size_t)pn * KK;
        float4 m = {-INFINITY, -INFINITY, -INFINITY, -INFINITY};
#pragma unroll
        for (int k = 0; k < KK; ++k) {
            int j = ip[k];
            float4 t = *(const float4*)&Tb[(size_t)j * 1024 + o];
            m.x = fmaxf(m.x, t.x); m.y = fmaxf(m.y, t.y);
            m.z = fmaxf(m.z, t.z); m.w = fmaxf(m.w, t.w);
        }
        float4 a = *(const float4*)&A[(size_t)pn * 1024 + o];
        float4 h;
        h.x = a.x + m.x; h.y = a.y + m.y; h.z = a.z + m.z; h.w = a.w + m.w;
        h.x = h.x > 0.f ? h.x : 0.2f * h.x;
        h.y = h.y > 0.f ? h.y : 0.2f * h.y;
        h.z = h.z > 0.f ? h.z : 0.2f * h.z;
        h.w = h.w > 0.f ? h.w : 0.2f * h.w;
        gm.x = fmaxf(gm.x, h.x); gm.y = fmaxf(gm.y, h.y);
        gm.z = fmaxf(gm.z, h.z); gm.w = fmaxf(gm.w, h.w);
    }
    *(float4*)&gp[((size_t)chunk * BB + b) * 1024 + o] = gm;
}

// ---------------------------------------------------------------------------
// Parallel tail: gmax2 (coalesced) then wave-per-output MLP stages.
__global__ void gmax2_kernel(const float* __restrict__ gp, float* __restrict__ g) {
    int i = blockIdx.x * 256 + threadIdx.x;      // 0..8191
    int b = i >> 10, o = i & 1023;
    float m = -INFINITY;
    for (int c = 0; c < GCH; ++c) m = fmaxf(m, gp[((size_t)c * BB + b) * 1024 + o]);
    g[(size_t)b * 1024 + o] = m;
}

// one wave per (b,t): H1[b][t] = m0b[t] + dot(G[b], m0w[:,t])   (1024 waves)
__global__ __launch_bounds__(256) void mlp1_kernel(
        const float* __restrict__ g, const float* __restrict__ m0w,
        const float* __restrict__ m0b, float* __restrict__ H1) {
    int wid = blockIdx.x * 4 + (threadIdx.x >> 6);
    int lane = threadIdx.x & 63;
    int b = wid >> 7, t = wid & 127;
    float s = 0.f;
    for (int f = lane; f < 1024; f += 64)
        s += g[(size_t)b * 1024 + f] * m0w[(size_t)f * 128 + t];
#pragma unroll
    for (int off = 32; off > 0; off >>= 1) s += __shfl_down(s, off);
    if (lane == 0) H1[(size_t)b * 128 + t] = s + m0b[t];
}

// one wave per (b,t): H2[b][t] = m1b[t] + dot(H1[b], m1w[:,t])   (512 waves)
__global__ __launch_bounds__(256) void mlp2_kernel(
        const float* __restrict__ H1, const float* __restrict__ m1w,
        const float* __restrict__ m1b, float* __restrict__ H2) {
    int wid = blockIdx.x * 4 + (threadIdx.x >> 6);
    int lane = threadIdx.x & 63;
    int b = wid >> 6, t = wid & 63;
    float s = 0.f;
    for (int f = lane; f < 128; f += 64)
        s += H1[(size_t)b * 128 + f] * m1w[(size_t)f * 64 + t];
#pragma unroll
    for (int off = 32; off > 0; off >>= 1) s += __shfl_down(s, off);
    if (lane == 0) H2[(size_t)b * 64 + t] = s + m1b[t];
}

// one wave per b: out[b] = m2b[0] + dot(H2[b], m2w)   (8 waves)
__global__ __launch_bounds__(256) void mlp3_kernel(
        const float* __restrict__ H2, const float* __restrict__ m2w,
        const float* __restrict__ m2b, float* __restrict__ out) {
    int b = blockIdx.x * 4 + (threadIdx.x >> 6);
    int lane = threadIdx.x & 63;
    if (b >= BB) return;
    float s = H2[(size_t)b * 64 + lane] * m2w[lane];
#pragma unroll
    for (int off = 32; off > 0; off >>= 1) s += __shfl_down(s, off);
    if (lane == 0) out[b] = s + m2b[0];
}

// ---------------------------------------------------------------------------
extern "C" void kernel_launch(void* const* d_in, const int* in_sizes, int n_in,
                              void* d_out, int out_size, void* d_ws, size_t ws_size,
                              hipStream_t stream) {
    const float* x0 = (const float*)d_in[0];
    const float* w[5], * bi[5];
    for (int i = 0; i < 5; ++i) { w[i] = (const float*)d_in[1 + 2 * i]; bi[i] = (const float*)d_in[2 + 2 * i]; }
    const float* m0w = (const float*)d_in[11]; const float* m0b = (const float*)d_in[12];
    const float* m1w = (const float*)d_in[13]; const float* m1b = (const float*)d_in[14];
    const float* m2w = (const float*)d_in[15]; const float* m2b = (const float*)d_in[16];

    const int fouts[5] = {64, 128, 256, 512, 1024};
    const int shifts[5] = {6, 7, 8, 9, 10};
    const int woff[5] = {0, 8192, 40960, 172032, 696320};
    const size_t WTALL = 2793472;   // shorts

    float* X0 = (float*)d_ws;
    float* X1 = X0 + (size_t)BN * 1024;
    float* T  = X1 + (size_t)BN * 1024;
    float* SQ = T  + (size_t)BN * 1024;
    int*   IDX = (int*)(SQ + BN);
    unsigned short* XSh = (unsigned short*)(IDX + (size_t)BN * KK);
    unsigned short* XSl = XSh + (size_t)BN * 512;
    unsigned short* WTall = XSl + (size_t)BN * 512;
    float* GP = (float*)(WTall + WTALL);
    float* G  = GP + (size_t)GCH * BB * 1024;
    float* H1 = G + (size_t)BB * 1024;
    float* H2 = H1 + (size_t)BB * 128;
    float* bufs[2] = {X0, X1};

    xsplit3_kernel<<<(BN + 255) / 256, 256, 0, stream>>>(x0, XSh, XSl, SQ);
    wsplit_all_kernel<<<(1396736 + 255) / 256, 256, 0, stream>>>(w[0], w[1], w[2], w[3], w[4], WTall);

    int fin = 3;
    for (int l = 0; l < 5; ++l) {
        int fout = fouts[l];
        float* nxt = bufs[l & 1];
        int Fg = (l == 0) ? 32 : fin;      // padded K for MFMA path

        // d2 halves: D2a = T, D2b = nxt (both dead until gemm2 writes them)
        dim3 gg2(136, BB);   // upper-triangle 128x128 tile pairs
        knn_gram_kernel<<<gg2, 256, 0, stream>>>(XSh, XSl, SQ, T, nxt, Fg);
        knn_select_kernel<<<BN / 4, 256, 0, stream>>>(T, nxt, IDX);

        dim3 gg(BN / 128, (2 * fout) / 128);
        gemm2_mfma_kernel<<<gg, 256, 0, stream>>>(XSh, XSl, WTall + woff[l], bi[l], nxt, T, Fg, fout);

        if (l < 4) {
            dim3 gmg(NN / 4, BB);
            gathermax_fused_kernel<<<gmg, 256, 0, stream>>>(nxt, T, IDX, XSh, XSl, SQ, shifts[l]);
        } else {
            dim3 gmg(GCH, BB);
            gathermax_gmax_kernel<<<gmg, 256, 0, stream>>>(nxt, T, IDX, GP);
        }

        fin = fout;
    }

    gmax2_kernel<<<32, 256, 0, stream>>>(GP, G);
    mlp1_kernel<<<256, 256, 0, stream>>>(G, m0w, m0b, H1);
    mlp2_kernel<<<128, 256, 0, stream>>>(H1, m1w, m1b, H2);
    mlp3_kernel<<<2, 256, 0, stream>>>(H2, m2w, m2b, (float*)d_out);
}